// Round 13
// baseline (153.909 us; speedup 1.0000x reference)
//
#include <hip/hip_runtime.h>
#include <math.h>

#define DIM 256
#define BATCH 16
#define NO 64
#define NI 512
#define NEG_SLOPE 0.01f
#define CSCALE 2.885390081777927f   // 2*log2(e): tanh(x) = 1 - 2/(exp2(CSCALE*x)+1)

// ---------------------------------------------------------------------------
// Kernel 1 (blocks 0..575): GEMM  out[r,h] = sum_d A[r,d] * W1[h, coff+d]
//   rows 0..1023    -> Eq[bo][h]        = exp2(CSCALE*(acc + b1[h]))  (A = q)
//   rows 1024..9215 -> Ek4[b][h/4][i][4]= exp2(CSCALE*acc)            (A = k)
// exp factorization: e^{2(qp+kp+b1)} = Eq * Ek -> attn sigmoid = fma+rcp.
// 64x64 tile, K-chunk 64, 4x4 microtile. Blocks 576..591: Wf -> WfT.
// ---------------------------------------------------------------------------
__global__ __launch_bounds__(256, 4) void proj_kernel(
    const float* __restrict__ q, const float* __restrict__ k,
    const float* __restrict__ W1, const float* __restrict__ b1,
    const float* __restrict__ Wf,
    float* __restrict__ Eq, float* __restrict__ Ek4, float* __restrict__ WfT)
{
  __shared__ float smem[8704];   // 34 KB: At[64][68] + Wt[64][68]

  const int t  = threadIdx.x;
  const int bx = blockIdx.x;

  if (bx >= 576) {
    const int tt = bx - 576;
    const int tr = tt >> 2, tc = tt & 3;
#pragma unroll
    for (int p = 0; p < 4; ++p) {
      int idx = p * 256 + t;
      int row = idx >> 4, j = idx & 15;
      float4 vv = *(const float4*)(Wf + (size_t)(tr * 64 + row) * 256 + tc * 64 + j * 4);
      *(float4*)&smem[row * 68 + j * 4] = vv;
    }
    __syncthreads();
#pragma unroll
    for (int p = 0; p < 4; ++p) {
      int idx = p * 256 + t;
      int row = idx >> 4, j = idx & 15;
      float4 ov;
      ov.x = smem[(j * 4 + 0) * 68 + row];
      ov.y = smem[(j * 4 + 1) * 68 + row];
      ov.z = smem[(j * 4 + 2) * 68 + row];
      ov.w = smem[(j * 4 + 3) * 68 + row];
      *(float4*)(WfT + (size_t)(tc * 64 + row) * 256 + tr * 64 + j * 4) = ov;
    }
    return;
  }

  float* At = smem;            // At[dk][row], stride 68
  float* Wt = smem + 4352;     // Wt[dk][h],   stride 68

  const int tx = t & 15;
  const int ty = t >> 4;
  const int mt = bx >> 2;
  const int nt = bx & 3;
  const int r0 = mt * 64;
  const int h0 = nt * 64;
  const bool isq = (r0 < BATCH * NO);
  const float* src = isq ? (q + (size_t)r0 * DIM)
                         : (k + (size_t)(r0 - BATCH * NO) * DIM);
  const int coff = isq ? 0 : DIM;

  float acc[4][4] = {};

  for (int c0 = 0; c0 < DIM; c0 += 64) {
    __syncthreads();
#pragma unroll
    for (int p = 0; p < 4; ++p) {
      int idx = p * 256 + t;
      int row = idx >> 4, j = idx & 15;
      float4 av = *(const float4*)(src + (size_t)row * DIM + c0 + j * 4);
      At[(4 * j + 0) * 68 + row] = av.x;
      At[(4 * j + 1) * 68 + row] = av.y;
      At[(4 * j + 2) * 68 + row] = av.z;
      At[(4 * j + 3) * 68 + row] = av.w;
      float4 wv = *(const float4*)(W1 + (size_t)(h0 + row) * (2 * DIM) + coff + c0 + j * 4);
      Wt[(4 * j + 0) * 68 + row] = wv.x;
      Wt[(4 * j + 1) * 68 + row] = wv.y;
      Wt[(4 * j + 2) * 68 + row] = wv.z;
      Wt[(4 * j + 3) * 68 + row] = wv.w;
    }
    __syncthreads();
#pragma unroll
    for (int dk = 0; dk < 64; ++dk) {
      float4 a4 = *(const float4*)&At[dk * 68 + ty * 4];
      float4 w4 = *(const float4*)&Wt[dk * 68 + tx * 4];
      const float ar[4] = {a4.x, a4.y, a4.z, a4.w};
      const float wr[4] = {w4.x, w4.y, w4.z, w4.w};
#pragma unroll
      for (int rr = 0; rr < 4; ++rr)
#pragma unroll
        for (int cc = 0; cc < 4; ++cc)
          acc[rr][cc] = fmaf(ar[rr], wr[cc], acc[rr][cc]);
    }
  }

  if (isq) {
    float4 bv = *(const float4*)(b1 + h0 + tx * 4);
    const float br[4] = {bv.x, bv.y, bv.z, bv.w};
#pragma unroll
    for (int rr = 0; rr < 4; ++rr) {
      int r = r0 + ty * 4 + rr;
      float4 ov;
      ov.x = __builtin_amdgcn_exp2f((acc[rr][0] + br[0]) * CSCALE);
      ov.y = __builtin_amdgcn_exp2f((acc[rr][1] + br[1]) * CSCALE);
      ov.z = __builtin_amdgcn_exp2f((acc[rr][2] + br[2]) * CSCALE);
      ov.w = __builtin_amdgcn_exp2f((acc[rr][3] + br[3]) * CSCALE);
      *(float4*)(Eq + (size_t)r * DIM + h0 + tx * 4) = ov;
    }
  } else {
    // Ek4 layout: Ek4[((b*64 + h/4)*NI + i)*4 + (h&3)]
    int ig0 = r0 - BATCH * NO;
    int b   = ig0 >> 9;
    int i0  = (ig0 & 511) + ty * 4;
    int hq0 = (h0 >> 2) + tx;          // this thread's h-quad
#pragma unroll
    for (int rr = 0; rr < 4; ++rr) {
      float4 ov;
      ov.x = __builtin_amdgcn_exp2f(acc[rr][0] * CSCALE);
      ov.y = __builtin_amdgcn_exp2f(acc[rr][1] * CSCALE);
      ov.z = __builtin_amdgcn_exp2f(acc[rr][2] * CSCALE);
      ov.w = __builtin_amdgcn_exp2f(acc[rr][3] * CSCALE);
      *(float4*)(Ek4 + ((size_t)(b * 64 + hq0) * NI + i0 + rr) * 4) = ov;
    }
  }
}

__device__ __forceinline__ void f4arr(float4 v, float* a) {
  a[0] = v.x; a[1] = v.y; a[2] = v.z; a[3] = v.w;
}

// ---------------------------------------------------------------------------
// Kernel 2: one block (1024 threads = 16 waves) per (b, o-quad). Grid 256 =
// 1 block/CU = 16 waves/CU (same wave count as the 2x512 config, but v and
// WfT are now read once per block serving FOUR o's). XCD-swizzled.
// phase 1: half = t>>9 owns o-pair {bo0+2*half, +1}; i = t&511. Paired-rcp
//          sigmoid (1 trans per 2 elements). Halves fully independent.
// phase 2: per-half softmax, no max-subtraction (|s| <= sum|W2|+|b2| ~ 13).
// phase 3: PV: 16 waves x 32 i each, v row read ONCE for all 4 o.
// phase 4: threads t<256 stream one WfT column for all 4 o.
// ---------------------------------------------------------------------------
__global__ __launch_bounds__(1024, 1) void attn_kernel(
    const float* __restrict__ Eq, const float* __restrict__ Ek4,
    const float* __restrict__ v, const int* __restrict__ mask,
    const float* __restrict__ W2, const float* __restrict__ b2,
    const float* __restrict__ WfT, const float* __restrict__ bf,
    float* __restrict__ out, float* __restrict__ attn_out)
{
  __shared__ float sc[4][NI];          // 8 KB
  __shared__ float pvp[16][4][DIM];    // 64 KB
  __shared__ float o0[4][DIM];         // 4 KB
  __shared__ float red4[16][2];
  __shared__ float redw[16];

  const int t    = threadIdx.x;
  const int lane = t & 63;
  const int wid  = t >> 6;             // 0..15
  const int half = t >> 9;             // 0..1 (o-pair index)
  const int i    = t & 511;

  const int blk  = blockIdx.x;
  const int tile = (blk & 7) * 32 + (blk >> 3);   // XCD swizzle
  const int b    = tile >> 4;
  const int bo0  = b * 64 + (tile & 15) * 4;

  // ---- sumW2 ----
  float partial = (t < DIM) ? W2[t] : 0.f;
#pragma unroll
  for (int off = 32; off >= 1; off >>= 1) partial += __shfl_xor(partial, off, 64);
  if (lane == 0) redw[wid] = partial;
  __syncthreads();
  float sumw2 = 0.f;
#pragma unroll
  for (int w = 0; w < 16; ++w) sumw2 += redw[w];
  const float base = sumw2 + b2[0];

  // ---- phase 1: scores for this half's o-pair, i = t&511 (paired-rcp) ----
  const float4* kb4 = (const float4*)Ek4 + (size_t)b * 64 * NI;  // [hq*NI + i]
  const float* qrow0 = Eq + (size_t)(bo0 + half * 2 + 0) * DIM;
  const float* qrow1 = Eq + (size_t)(bo0 + half * 2 + 1) * DIM;

  float acc0 = 0.f, acc1 = 0.f;
#pragma unroll 8
  for (int hq = 0; hq < 64; ++hq) {
    float4 kq = kb4[(size_t)hq * NI + i];
    float wr[4], q0r[4], q1r[4], kv[4];
    f4arr(*(const float4*)(W2 + hq * 4), wr);        // wave-uniform -> s_load
    f4arr(*(const float4*)(qrow0 + hq * 4), q0r);
    f4arr(*(const float4*)(qrow1 + hq * 4), q1r);
    f4arr(kq, kv);
#pragma unroll
    for (int pr = 0; pr < 2; ++pr) {                 // pairs (0,1) and (2,3)
      const int ea = pr * 2, eb = pr * 2 + 1;
      float A0 = fmaf(q0r[ea], kv[ea], 1.f);
      float B0 = fmaf(q0r[eb], kv[eb], 1.f);
      float N0 = fmaf(wr[eb], A0, wr[ea] * B0);
      acc0 = fmaf(N0, __builtin_amdgcn_rcpf(A0 * B0), acc0);
      float A1 = fmaf(q1r[ea], kv[ea], 1.f);
      float B1 = fmaf(q1r[eb], kv[eb], 1.f);
      float N1 = fmaf(wr[eb], A1, wr[ea] * B1);
      acc1 = fmaf(N1, __builtin_amdgcn_rcpf(A1 * B1), acc1);
    }
  }

  const int mv = mask[(size_t)b * NI + i];
  float s0 = base - 2.f * acc0;
  float s1 = base - 2.f * acc1;
  if (mv) { s0 = -INFINITY; s1 = -INFINITY; }

  // ---- phase 2: per-half softmaxes over 512 i, no max-subtraction ----
  float p0 = __builtin_amdgcn_exp2f(s0 * 1.4426950408889634f);   // exp(-inf)=0
  float p1 = __builtin_amdgcn_exp2f(s1 * 1.4426950408889634f);
  float ps0 = p0, ps1 = p1;
#pragma unroll
  for (int off = 32; off >= 1; off >>= 1) {
    ps0 += __shfl_xor(ps0, off, 64);
    ps1 += __shfl_xor(ps1, off, 64);
  }
  __syncthreads();               // redw reads done; red4 safe
  if (lane == 0) { red4[wid][0] = ps0; red4[wid][1] = ps1; }
  __syncthreads();
  float ss0 = 0.f, ss1 = 0.f;
#pragma unroll
  for (int w = 0; w < 8; ++w) {       // this half's 8 waves
    ss0 += red4[half * 8 + w][0];
    ss1 += red4[half * 8 + w][1];
  }
  const float a0 = p0 * __builtin_amdgcn_rcpf(ss0);
  const float a1 = p1 * __builtin_amdgcn_rcpf(ss1);
  sc[half * 2 + 0][i] = a0;
  sc[half * 2 + 1][i] = a1;
  attn_out[(size_t)(bo0 + half * 2 + 0) * NI + i] = a0;
  attn_out[(size_t)(bo0 + half * 2 + 1) * NI + i] = a1;
  __syncthreads();

  // ---- phase 3: PV. wave wid: i in [wid*32, wid*32+32), lane = 4 d's,
  //      v row read once, serves all 4 o ----
  {
    const int d4 = lane;
    float4 av[4];
#pragma unroll
    for (int oo = 0; oo < 4; ++oo) av[oo] = make_float4(0.f, 0.f, 0.f, 0.f);
    const float4* vb4 = (const float4*)(v + (size_t)b * NI * DIM);
#pragma unroll 2
    for (int ib = wid * 32; ib < wid * 32 + 32; ib += 4) {
      float sa[4][4];
#pragma unroll
      for (int oo = 0; oo < 4; ++oo) f4arr(*(const float4*)&sc[oo][ib], sa[oo]);
#pragma unroll
      for (int j = 0; j < 4; ++j) {
        float4 vv = vb4[(size_t)(ib + j) * 64 + d4];
#pragma unroll
        for (int oo = 0; oo < 4; ++oo) {
          av[oo].x = fmaf(sa[oo][j], vv.x, av[oo].x);
          av[oo].y = fmaf(sa[oo][j], vv.y, av[oo].y);
          av[oo].z = fmaf(sa[oo][j], vv.z, av[oo].z);
          av[oo].w = fmaf(sa[oo][j], vv.w, av[oo].w);
        }
      }
    }
#pragma unroll
    for (int oo = 0; oo < 4; ++oo) *(float4*)&pvp[wid][oo][d4 * 4] = av[oo];
  }
  __syncthreads();
  {
    const int oo = t >> 8, d = t & 255;     // 1024 threads cover 4 x 256
    float sacc = 0.f;
#pragma unroll
    for (int w = 0; w < 16; ++w) sacc += pvp[w][oo][d];
    o0[oo][d] = sacc;
  }
  __syncthreads();

  // ---- phase 4: threads t<256 stream WfT column d once for ALL 4 o ----
  if (t < DIM) {
    const int d = t;
    float f0 = 0.f, f1 = 0.f, f2 = 0.f, f3 = 0.f;
#pragma unroll 8
    for (int e4 = 0; e4 < 64; ++e4) {
      float oa[4], ob[4], oc[4], od[4];
      f4arr(*(const float4*)&o0[0][e4 * 4], oa);
      f4arr(*(const float4*)&o0[1][e4 * 4], ob);
      f4arr(*(const float4*)&o0[2][e4 * 4], oc);
      f4arr(*(const float4*)&o0[3][e4 * 4], od);
#pragma unroll
      for (int c = 0; c < 4; ++c) {
        float wv = WfT[(size_t)(e4 * 4 + c) * DIM + d];
        f0 = fmaf(oa[c], wv, f0);
        f1 = fmaf(ob[c], wv, f1);
        f2 = fmaf(oc[c], wv, f2);
        f3 = fmaf(od[c], wv, f3);
      }
    }
    float bfv = bf[d];
    f0 += bfv; f1 += bfv; f2 += bfv; f3 += bfv;
    f0 = (f0 >= 0.f) ? f0 : NEG_SLOPE * f0;
    f1 = (f1 >= 0.f) ? f1 : NEG_SLOPE * f1;
    f2 = (f2 >= 0.f) ? f2 : NEG_SLOPE * f2;
    f3 = (f3 >= 0.f) ? f3 : NEG_SLOPE * f3;
    out[(size_t)(bo0 + 0) * DIM + d] = f0;
    out[(size_t)(bo0 + 1) * DIM + d] = f1;
    out[(size_t)(bo0 + 2) * DIM + d] = f2;
    out[(size_t)(bo0 + 3) * DIM + d] = f3;
  }
}

// ---------------------------------------------------------------------------
extern "C" void kernel_launch(void* const* d_in, const int* in_sizes, int n_in,
                              void* d_out, int out_size, void* d_ws, size_t ws_size,
                              hipStream_t stream) {
  const float* q    = (const float*)d_in[0];
  const float* k    = (const float*)d_in[1];
  const float* v    = (const float*)d_in[2];
  const int*   mask = (const int*)d_in[3];
  const float* W1   = (const float*)d_in[4];
  const float* b1   = (const float*)d_in[5];
  const float* W2   = (const float*)d_in[6];
  const float* b2   = (const float*)d_in[7];
  const float* Wf   = (const float*)d_in[8];
  const float* bf   = (const float*)d_in[9];

  float* out      = (float*)d_out;                    // (16,64,256)
  float* attn_out = out + (size_t)BATCH * NO * DIM;   // (16,64,512)

  float* Eq  = (float*)d_ws;                          // 1024 x 256
  float* Ek4 = Eq + (size_t)BATCH * NO * DIM;         // 16 x 64 x 512 x 4
  float* WfT = Ek4 + (size_t)BATCH * DIM * NI;        // 256 x 256

  proj_kernel<<<592, 256, 0, stream>>>(q, k, W1, b1, Wf, Eq, Ek4, WfT);
  attn_kernel<<<(BATCH * NO) / 4, 1024, 0, stream>>>(Eq, Ek4, v, mask, W2, b2,
                                                     WfT, bf, out, attn_out);
}

// Round 14
// 136.698 us; speedup vs baseline: 1.1259x; 1.1259x over previous
//
#include <hip/hip_runtime.h>
#include <math.h>

#define DIM 256
#define BATCH 16
#define NO 64
#define NI 512
#define NEG_SLOPE 0.01f
#define CSCALE 2.885390081777927f   // 2*log2(e): tanh(x) = 1 - 2/(exp2(CSCALE*x)+1)
#define OT 2                        // o's per attn thread

// ---------------------------------------------------------------------------
// Kernel 0: per-batch mask compaction. cnt[b] = #unmasked, idx[b][j] = i of
// j-th unmasked column, pos[b][i] = compacted slot (or -1 if masked).
// ---------------------------------------------------------------------------
__global__ __launch_bounds__(512) void mask_scan_kernel(
    const int* __restrict__ mask, int* __restrict__ idx,
    int* __restrict__ posArr, int* __restrict__ cnt)
{
  __shared__ int wtot[8];
  __shared__ int woff[8];
  const int b = blockIdx.x, t = threadIdx.x;
  const int lane = t & 63, wid = t >> 6;
  const int unm = (mask[b * NI + t] == 0) ? 1 : 0;
  unsigned long long bal = __ballot(unm);
  int my  = __popcll(bal & ((1ull << lane) - 1ull));
  if (lane == 0) wtot[wid] = __popcll(bal);
  __syncthreads();
  if (t == 0) {
    int acc = 0;
    for (int w = 0; w < 8; ++w) { woff[w] = acc; acc += wtot[w]; }
    cnt[b] = acc;
  }
  __syncthreads();
  int pos = woff[wid] + my;
  if (unm) idx[b * NI + pos] = t;
  posArr[b * NI + t] = unm ? pos : -1;
}

// ---------------------------------------------------------------------------
// Kernel 1 (blocks 0..575): GEMM  out[r,h] = sum_d A[r,d] * W1[h, coff+d]
//   rows 0..1023    -> Eq[bo][h] = exp2(CSCALE*(acc + b1[h]))  (A = q)
//   rows 1024..9215 -> Ek4[b][h/4][pos[i]][4] = exp2(CSCALE*acc)  (A = k,
//                      COMPACTED: masked columns dropped so attn reads are
//                      contiguous over j)
// 64x64 tile, K-chunk 64, 4x4 microtile. Blocks 576..591: Wf -> WfT.
// ---------------------------------------------------------------------------
__global__ __launch_bounds__(256, 4) void proj_kernel(
    const float* __restrict__ q, const float* __restrict__ k,
    const float* __restrict__ W1, const float* __restrict__ b1,
    const float* __restrict__ Wf, const int* __restrict__ posArr,
    float* __restrict__ Eq, float* __restrict__ Ek4, float* __restrict__ WfT)
{
  __shared__ float smem[8704];   // 34 KB: At[64][68] + Wt[64][68]

  const int t  = threadIdx.x;
  const int bx = blockIdx.x;

  if (bx >= 576) {
    const int tt = bx - 576;
    const int tr = tt >> 2, tc = tt & 3;
#pragma unroll
    for (int p = 0; p < 4; ++p) {
      int idx2 = p * 256 + t;
      int row = idx2 >> 4, j = idx2 & 15;
      float4 vv = *(const float4*)(Wf + (size_t)(tr * 64 + row) * 256 + tc * 64 + j * 4);
      *(float4*)&smem[row * 68 + j * 4] = vv;
    }
    __syncthreads();
#pragma unroll
    for (int p = 0; p < 4; ++p) {
      int idx2 = p * 256 + t;
      int row = idx2 >> 4, j = idx2 & 15;
      float4 ov;
      ov.x = smem[(j * 4 + 0) * 68 + row];
      ov.y = smem[(j * 4 + 1) * 68 + row];
      ov.z = smem[(j * 4 + 2) * 68 + row];
      ov.w = smem[(j * 4 + 3) * 68 + row];
      *(float4*)(WfT + (size_t)(tc * 64 + row) * 256 + tr * 64 + j * 4) = ov;
    }
    return;
  }

  float* At = smem;            // At[dk][row], stride 68
  float* Wt = smem + 4352;     // Wt[dk][h],   stride 68

  const int tx = t & 15;
  const int ty = t >> 4;
  const int mt = bx >> 2;
  const int nt = bx & 3;
  const int r0 = mt * 64;
  const int h0 = nt * 64;
  const bool isq = (r0 < BATCH * NO);
  const float* src = isq ? (q + (size_t)r0 * DIM)
                         : (k + (size_t)(r0 - BATCH * NO) * DIM);
  const int coff = isq ? 0 : DIM;

  float acc[4][4] = {};

  for (int c0 = 0; c0 < DIM; c0 += 64) {
    __syncthreads();
#pragma unroll
    for (int p = 0; p < 4; ++p) {
      int idx2 = p * 256 + t;
      int row = idx2 >> 4, j = idx2 & 15;
      float4 av = *(const float4*)(src + (size_t)row * DIM + c0 + j * 4);
      At[(4 * j + 0) * 68 + row] = av.x;
      At[(4 * j + 1) * 68 + row] = av.y;
      At[(4 * j + 2) * 68 + row] = av.z;
      At[(4 * j + 3) * 68 + row] = av.w;
      float4 wv = *(const float4*)(W1 + (size_t)(h0 + row) * (2 * DIM) + coff + c0 + j * 4);
      Wt[(4 * j + 0) * 68 + row] = wv.x;
      Wt[(4 * j + 1) * 68 + row] = wv.y;
      Wt[(4 * j + 2) * 68 + row] = wv.z;
      Wt[(4 * j + 3) * 68 + row] = wv.w;
    }
    __syncthreads();
#pragma unroll
    for (int dk = 0; dk < 64; ++dk) {
      float4 a4 = *(const float4*)&At[dk * 68 + ty * 4];
      float4 w4 = *(const float4*)&Wt[dk * 68 + tx * 4];
      const float ar[4] = {a4.x, a4.y, a4.z, a4.w};
      const float wr[4] = {w4.x, w4.y, w4.z, w4.w};
#pragma unroll
      for (int rr = 0; rr < 4; ++rr)
#pragma unroll
        for (int cc = 0; cc < 4; ++cc)
          acc[rr][cc] = fmaf(ar[rr], wr[cc], acc[rr][cc]);
    }
  }

  if (isq) {
    float4 bv = *(const float4*)(b1 + h0 + tx * 4);
    const float br[4] = {bv.x, bv.y, bv.z, bv.w};
#pragma unroll
    for (int rr = 0; rr < 4; ++rr) {
      int r = r0 + ty * 4 + rr;
      float4 ov;
      ov.x = __builtin_amdgcn_exp2f((acc[rr][0] + br[0]) * CSCALE);
      ov.y = __builtin_amdgcn_exp2f((acc[rr][1] + br[1]) * CSCALE);
      ov.z = __builtin_amdgcn_exp2f((acc[rr][2] + br[2]) * CSCALE);
      ov.w = __builtin_amdgcn_exp2f((acc[rr][3] + br[3]) * CSCALE);
      *(float4*)(Eq + (size_t)r * DIM + h0 + tx * 4) = ov;
    }
  } else {
    // Ek4 layout (compacted): Ek4[((b*64 + h/4)*NI + pos[i])*4 + (h&3)]
    int ig0 = r0 - BATCH * NO;
    int b   = ig0 >> 9;
    int i0  = (ig0 & 511) + ty * 4;
    int hq0 = (h0 >> 2) + tx;          // this thread's h-quad
#pragma unroll
    for (int rr = 0; rr < 4; ++rr) {
      int pos = posArr[b * NI + i0 + rr];
      if (pos >= 0) {
        float4 ov;
        ov.x = __builtin_amdgcn_exp2f(acc[rr][0] * CSCALE);
        ov.y = __builtin_amdgcn_exp2f(acc[rr][1] * CSCALE);
        ov.z = __builtin_amdgcn_exp2f(acc[rr][2] * CSCALE);
        ov.w = __builtin_amdgcn_exp2f(acc[rr][3] * CSCALE);
        *(float4*)(Ek4 + ((size_t)(b * 64 + hq0) * NI + pos) * 4) = ov;
      }
    }
  }
}

__device__ __forceinline__ void f4arr(float4 v, float* a) {
  a[0] = v.x; a[1] = v.y; a[2] = v.z; a[3] = v.w;
}

// ---------------------------------------------------------------------------
// Kernel 2: one block (512 threads) per (b, o-pair). Grid 512. XCD-swizzled.
// MASK-COMPACTED: thread j < cnt[b] handles the j-th UNMASKED column only —
// phase-1 work and Ek/v L2 traffic ~halve (mask ~ Bernoulli(0.5)).
// phase 1: paired-rcp sigmoid over compacted Ek4 (coalesced).
// phase 2: softmax over compacted set, no max-subtraction; attn_out scattered
//          back via pos (masked -> exact 0).
// phase 3: PV over compacted rows (row base via LDS idx, coalesced in d).
// phase 4: both o's per thread, shared WfT column.
// ---------------------------------------------------------------------------
__global__ __launch_bounds__(512, 4) void attn_kernel(
    const float* __restrict__ Eq, const float* __restrict__ Ek4,
    const float* __restrict__ v, const int* __restrict__ idx,
    const int* __restrict__ posArr, const int* __restrict__ cnt,
    const float* __restrict__ W2, const float* __restrict__ b2,
    const float* __restrict__ WfT, const float* __restrict__ bf,
    float* __restrict__ out, float* __restrict__ attn_out)
{
  __shared__ float sc[OT][NI];        // 4 KB (compacted attn weights)
  __shared__ int   idxs[NI];          // 2 KB
  __shared__ float pvp[8][OT][DIM];   // 16 KB
  __shared__ float o0[OT][DIM];       // 2 KB
  __shared__ float red4[8][OT];
  __shared__ float redw[8];

  const int t    = threadIdx.x;
  const int lane = t & 63;
  const int wid  = t >> 6;

  const int blk  = blockIdx.x;
  const int tile = (blk & 7) * 64 + (blk >> 3);   // XCD swizzle
  const int b    = tile >> 5;
  const int bo0  = b * 64 + (tile & 31) * OT;

  const int cntb = cnt[b];
  idxs[t] = idx[b * NI + t];
  const int myPos = posArr[b * NI + t];    // for attn_out scatter-back

  // ---- sumW2 ----
  float partial = (t < DIM) ? W2[t] : 0.f;
#pragma unroll
  for (int off = 32; off >= 1; off >>= 1) partial += __shfl_xor(partial, off, 64);
  if (lane == 0) redw[wid] = partial;
  __syncthreads();
  float sumw2 = 0.f;
#pragma unroll
  for (int w = 0; w < 8; ++w) sumw2 += redw[w];
  const float base = sumw2 + b2[0];

  // ---- phase 1: scores for compacted column j = t (paired-rcp) ----
  const int j = t;
  const bool active = (j < cntb);
  const int jc = active ? j : (cntb > 0 ? cntb - 1 : 0);   // clamped safe index
  const float4* kb4 = (const float4*)Ek4 + (size_t)b * 64 * NI;  // [hq*NI + j]
  const float* qrow0 = Eq + (size_t)(bo0 + 0) * DIM;
  const float* qrow1 = Eq + (size_t)(bo0 + 1) * DIM;

  float acc0 = 0.f, acc1 = 0.f;
  if (wid * 64 < cntb) {                 // wave-uniform skip of dead waves
#pragma unroll 8
    for (int hq = 0; hq < 64; ++hq) {
      float4 kq = kb4[(size_t)hq * NI + jc];
      float wr[4], q0r[4], q1r[4], kv[4];
      f4arr(*(const float4*)(W2 + hq * 4), wr);      // wave-uniform -> s_load
      f4arr(*(const float4*)(qrow0 + hq * 4), q0r);
      f4arr(*(const float4*)(qrow1 + hq * 4), q1r);
      f4arr(kq, kv);
#pragma unroll
      for (int pr = 0; pr < 2; ++pr) {               // pairs (0,1), (2,3)
        const int ea = pr * 2, eb = pr * 2 + 1;
        float A0 = fmaf(q0r[ea], kv[ea], 1.f);
        float B0 = fmaf(q0r[eb], kv[eb], 1.f);
        float N0 = fmaf(wr[eb], A0, wr[ea] * B0);
        acc0 = fmaf(N0, __builtin_amdgcn_rcpf(A0 * B0), acc0);
        float A1 = fmaf(q1r[ea], kv[ea], 1.f);
        float B1 = fmaf(q1r[eb], kv[eb], 1.f);
        float N1 = fmaf(wr[eb], A1, wr[ea] * B1);
        acc1 = fmaf(N1, __builtin_amdgcn_rcpf(A1 * B1), acc1);
      }
    }
  }

  float s0 = active ? (base - 2.f * acc0) : -INFINITY;
  float s1 = active ? (base - 2.f * acc1) : -INFINITY;

  // ---- phase 2: softmax over compacted set, no max-subtraction ----
  // |s| <= sum|W2| + |b2| ~ 13 -> exp2 safe; exp2(-inf) = 0 for inactive.
  float p0 = __builtin_amdgcn_exp2f(s0 * 1.4426950408889634f);
  float p1 = __builtin_amdgcn_exp2f(s1 * 1.4426950408889634f);
  float ps0 = p0, ps1 = p1;
#pragma unroll
  for (int off = 32; off >= 1; off >>= 1) {
    ps0 += __shfl_xor(ps0, off, 64);
    ps1 += __shfl_xor(ps1, off, 64);
  }
  __syncthreads();               // redw reads done; red4 safe
  if (lane == 0) { red4[wid][0] = ps0; red4[wid][1] = ps1; }
  __syncthreads();
  float ss0 = 0.f, ss1 = 0.f;
#pragma unroll
  for (int w = 0; w < 8; ++w) { ss0 += red4[w][0]; ss1 += red4[w][1]; }
  const float a0 = p0 * __builtin_amdgcn_rcpf(ss0);
  const float a1 = p1 * __builtin_amdgcn_rcpf(ss1);
  sc[0][j] = a0;                 // compacted slot (0 for inactive j)
  sc[1][j] = a1;
  __syncthreads();

  // attn_out scatter-back: original column i = t; masked -> exact 0
  {
    float w0 = (myPos >= 0) ? sc[0][myPos] : 0.f;
    float w1 = (myPos >= 0) ? sc[1][myPos] : 0.f;
    attn_out[(size_t)(bo0 + 0) * NI + t] = w0;
    attn_out[(size_t)(bo0 + 1) * NI + t] = w1;
  }

  // ---- phase 3: PV over compacted rows. wave wid: j in [wid*64, +64)∩cnt ----
  {
    const int d4 = lane;
    float4 av0 = {0.f, 0.f, 0.f, 0.f};
    float4 av1 = {0.f, 0.f, 0.f, 0.f};
    const float4* vb4 = (const float4*)(v + (size_t)b * NI * DIM);
    const int jend = min(wid * 64 + 64, cntb);
#pragma unroll 4
    for (int jb = wid * 64; jb < jend; ++jb) {
      int row = idxs[jb];                      // LDS broadcast (uniform)
      float sa0 = sc[0][jb], sa1 = sc[1][jb];  // LDS broadcast
      float4 vv = vb4[(size_t)row * 64 + d4];
      av0.x = fmaf(sa0, vv.x, av0.x);
      av0.y = fmaf(sa0, vv.y, av0.y);
      av0.z = fmaf(sa0, vv.z, av0.z);
      av0.w = fmaf(sa0, vv.w, av0.w);
      av1.x = fmaf(sa1, vv.x, av1.x);
      av1.y = fmaf(sa1, vv.y, av1.y);
      av1.z = fmaf(sa1, vv.z, av1.z);
      av1.w = fmaf(sa1, vv.w, av1.w);
    }
    *(float4*)&pvp[wid][0][d4 * 4] = av0;      // dead waves store zeros
    *(float4*)&pvp[wid][1][d4 * 4] = av1;
  }
  __syncthreads();
  {
    int oo = t >> 8, d = t & 255;
    float sacc = 0.f;
#pragma unroll
    for (int w = 0; w < 8; ++w) sacc += pvp[w][oo][d];
    o0[oo][d] = sacc;
  }
  __syncthreads();

  // ---- phase 4: threads t<256 compute BOTH o's, one WfT column load ----
  if (t < DIM) {
    const int d = t;
    float f0 = 0.f, f1 = 0.f;
#pragma unroll 8
    for (int e4 = 0; e4 < 64; ++e4) {
      float oa[4], ob[4];
      f4arr(*(const float4*)&o0[0][e4 * 4], oa);
      f4arr(*(const float4*)&o0[1][e4 * 4], ob);
#pragma unroll
      for (int c = 0; c < 4; ++c) {
        float wv = WfT[(size_t)(e4 * 4 + c) * DIM + d];
        f0 = fmaf(oa[c], wv, f0);
        f1 = fmaf(ob[c], wv, f1);
      }
    }
    float bfv = bf[d];
    f0 += bfv; f1 += bfv;
    f0 = (f0 >= 0.f) ? f0 : NEG_SLOPE * f0;
    f1 = (f1 >= 0.f) ? f1 : NEG_SLOPE * f1;
    out[(size_t)(bo0 + 0) * DIM + d] = f0;
    out[(size_t)(bo0 + 1) * DIM + d] = f1;
  }
}

// ---------------------------------------------------------------------------
extern "C" void kernel_launch(void* const* d_in, const int* in_sizes, int n_in,
                              void* d_out, int out_size, void* d_ws, size_t ws_size,
                              hipStream_t stream) {
  const float* q    = (const float*)d_in[0];
  const float* k    = (const float*)d_in[1];
  const float* v    = (const float*)d_in[2];
  const int*   mask = (const int*)d_in[3];
  const float* W1   = (const float*)d_in[4];
  const float* b1   = (const float*)d_in[5];
  const float* W2   = (const float*)d_in[6];
  const float* b2   = (const float*)d_in[7];
  const float* Wf   = (const float*)d_in[8];
  const float* bf   = (const float*)d_in[9];

  float* out      = (float*)d_out;                    // (16,64,256)
  float* attn_out = out + (size_t)BATCH * NO * DIM;   // (16,64,512)

  float* Eq   = (float*)d_ws;                         // 1024 x 256
  float* Ek4  = Eq + (size_t)BATCH * NO * DIM;        // 16 x 64 x 512 x 4
  float* WfT  = Ek4 + (size_t)BATCH * DIM * NI;       // 256 x 256
  int*   idx  = (int*)(WfT + (size_t)DIM * DIM);      // 16 x 512
  int*   pos  = idx + BATCH * NI;                     // 16 x 512
  int*   cnt  = pos + BATCH * NI;                     // 16

  mask_scan_kernel<<<BATCH, 512, 0, stream>>>(mask, idx, pos, cnt);
  proj_kernel<<<592, 256, 0, stream>>>(q, k, W1, b1, Wf, pos, Eq, Ek4, WfT);
  attn_kernel<<<(BATCH * NO) / OT, 512, 0, stream>>>(Eq, Ek4, v, idx, pos, cnt,
                                                     W2, b2, WfT, bf, out, attn_out);
}